// Round 12
// baseline (256.466 us; speedup 1.0000x reference)
//
#include <hip/hip_runtime.h>

#define T_    8
#define H_    28
#define W_    28
#define NSP   6272      // T*H*W
#define NTOKS 6273
#define DIM   192
#define HEADS 2
#define HD    96
#define SCALE2_ 0.14724441f             // 96^-0.5 * log2(e)  (exp -> exp2 domain)
#define RINV_   6.7914276f              // sqrt(96) * ln(2)   (residual undo of SCALE2_)
#define LOG2E_  1.4426950408889634f
#define EPS_  1e-5f

#define QT    128                       // q-rows per block (8 waves x 16)
#define KT    64
#define QB    50                        // ceil(6273/128)
#define NTILES_TOT 99
#define NSPL  5                         // 50*2*5 = 500 blocks <= 512 capacity => ONE round
#define SPT   20                        // ceil(99/5) tiles per split
#define KCH   160                       // extended K channels (96 + 64 one-hot)
#define VT_LD 6400                      // padded vbT row length (tokens)
#define NSTRIP 1569                     // 1 cls + 8*28*7 spatial strips (4 x-tokens each)

using bf16x8 = __attribute__((ext_vector_type(8))) short;
using f32x4  = __attribute__((ext_vector_type(4))) float;
typedef unsigned short u16;
typedef unsigned int   u32;

__device__ __forceinline__ u16 f2b(float f) {   // fp32 -> bf16 bits, RNE
    u32 u = __builtin_bit_cast(u32, f);
    u += 0x7fffu + ((u >> 16) & 1u);
    return (u16)(u >> 16);
}
__device__ __forceinline__ float b2f(u16 v) {
    u32 u = ((u32)v) << 16;
    return __builtin_bit_cast(float, u);
}

// async global->LDS 16B: LDS dest is wave-uniform base + lane*16 (m104)
__device__ __forceinline__ void async16(const void* g, void* l) {
    __builtin_amdgcn_global_load_lds(
        (const __attribute__((address_space(1))) u32*)g,
        (__attribute__((address_space(3))) u32*)l, 16, 0, 0);
}

// ------- Kernel 0: fp32 -> bf16 conversion (x, qkv_w, proj_w) + pool-weight transpose -------
__global__ __launch_bounds__(256) void cvt_bf16(
    const float* __restrict__ s0, u16* __restrict__ d0, int n0,
    const float* __restrict__ s1, u16* __restrict__ d1, int n1,
    const float* __restrict__ s2, u16* __restrict__ d2, int n2,
    const float* __restrict__ wq, const float* __restrict__ wk,
    const float* __restrict__ wv, float* __restrict__ wT)
{
    const int nw = 3 * 27 * 96;
    int tot = n0 + n1 + n2 + nw;
    for (int i = blockIdx.x * 256 + threadIdx.x; i < tot; i += gridDim.x * 256) {
        if (i < n0)                 d0[i] = f2b(s0[i]);
        else if (i < n0 + n1)       d1[i - n0] = f2b(s1[i - n0]);
        else if (i < n0 + n1 + n2)  d2[i - n0 - n1] = f2b(s2[i - n0 - n1]);
        else {
            int j = i - n0 - n1 - n2;       // which*2592 + widx*96 + c
            int which = j / 2592, r = j % 2592;
            int widx = r / 96, c = r % 96;
            const float* src = which == 0 ? wq : (which == 1 ? wk : wv);
            wT[j] = src[c * 27 + widx];
        }
    }
}

// ---------------- Kernel 1: OUT[m][n] = sum_k A[m][k]*W[n][k] + bias[n] (MFMA) --------
__global__ __launch_bounds__(256, 3) void gemm_bf16(
    const u16* __restrict__ A, const u16* __restrict__ Wt,
    const float* __restrict__ bias, float* __restrict__ outf,
    u16* __restrict__ outb, int M, int ldo)
{
    __shared__ __align__(16) u16 als[24 * 512];
    __shared__ __align__(16) u16 wls[24 * 512];
    const int m0 = blockIdx.x * 64, n0 = blockIdx.y * 64;
    const int tid  = threadIdx.x;
    const int w    = tid >> 6;
    const int lane = tid & 63;
    const int quad = lane >> 4;
    const int l16  = lane & 15;
    {
        int m = m0 + lane; if (m > M - 1) m = M - 1;
        const u16* ab = A  + (size_t)m * 192;
        const u16* wb = Wt + (size_t)(n0 + lane) * 192;
        #pragma unroll
        for (int i = 0; i < 6; ++i) {
            int g = w * 6 + i;              // 0..23, covers k = g*8..g*8+7
            async16(ab + g * 8, als + g * 512);
            async16(wb + g * 8, wls + g * 512);
        }
    }
    __syncthreads();
    f32x4 acc[4];
    #pragma unroll
    for (int mt = 0; mt < 4; ++mt) acc[mt] = (f32x4){0,0,0,0};
    #pragma unroll
    for (int cc = 0; cc < 6; ++cc) {
        bf16x8 bf = *(const bf16x8*)(wls + (((cc * 4 + quad) * 64) + w * 16 + l16) * 8);
        #pragma unroll
        for (int mt = 0; mt < 4; ++mt) {
            bf16x8 af = *(const bf16x8*)(als + (((cc * 4 + quad) * 64) + mt * 16 + l16) * 8);
            acc[mt] = __builtin_amdgcn_mfma_f32_16x16x32_bf16(af, bf, acc[mt], 0, 0, 0);
        }
    }
    float bj = bias[n0 + w * 16 + l16];
    #pragma unroll
    for (int mt = 0; mt < 4; ++mt) {
        #pragma unroll
        for (int rr = 0; rr < 4; ++rr) {
            int row = m0 + mt * 16 + quad * 4 + rr;
            if (row < M) {
                float v = acc[mt][rr] + bj;
                size_t off = (size_t)row * ldo + n0 + w * 16 + l16;
                if (outb) outb[off] = f2b(v);
                else      outf[off] = v;
            }
        }
    }
}

// ------------- Kernel 2: pool+LN v9 — 1-wave-per-matrix blocks (concurrency fix) -----
// R9-R11 post-mortem: per-block wall ~31K cycles vs ~3.5K VALU; only 2.3 blocks/CU
// co-resident -> ~90% latency stall that 3 micro-fixes (weight regs, weight nothing,
// tail parallelize) failed to move. v9 splits each 3-wave {q,k,v} block into 3
// INDEPENDENT 1-wave blocks, each staging only its own mat slab (11.3KB sls + 1.5KB
// qls = 12.8KB LDS => 12 blocks/CU, 5x deeper overlap). Per-lane conv code identical
// to the proven R9 form. Total VALU work (~19us) is the new floor.
__global__ __launch_bounds__(64) void pool_ln9(
    const u16* __restrict__ qkvb, const float* __restrict__ wT,
    const float* __restrict__ gq, const float* __restrict__ bq,
    const float* __restrict__ gk, const float* __restrict__ bk,
    const float* __restrict__ gv, const float* __restrict__ bv,
    const float* __restrict__ rel_h, const float* __restrict__ rel_w,
    const float* __restrict__ rel_t,
    u16* __restrict__ qbb, u16* __restrict__ kx, u16* __restrict__ vbb,
    float* __restrict__ bt, float* __restrict__ bh, float* __restrict__ bw)
{
    // sls[rr*6+xx][96]: one mat's slab. 648 16B-chunks padded to 704 (11,264 B).
    __shared__ __align__(16) u16 sls[5632];
    __shared__ __align__(16) float qls[4][96];   // q-blocks only
    const int s   = blockIdx.x;          // strip (0 = cls)
    const int wid = blockIdx.y;          // 0=q 1=k 2=v
    const int h   = blockIdx.z;          // head
    const int lane = threadIdx.x;        // 0..63 (one wave)
    const bool two = (lane < 32);

    const float* gg = wid == 0 ? gq : (wid == 1 ? gk : gv);
    const float* bb = wid == 0 ? bq : (wid == 1 ? bk : bv);
    const float g0 = gg[lane], b0 = bb[lane];
    const float g1 = two ? gg[64 + lane] : 0.f;
    const float b1 = two ? bb[64 + lane] : 0.f;
    const int col0 = wid * DIM + h * HD;

    if (s == 0) {
        float v0 = b2f(qkvb[col0 + lane]);
        float v1 = two ? b2f(qkvb[col0 + 64 + lane]) : 0.f;
        float s1 = v0 + v1, s2 = v0 * v0 + v1 * v1;
        #pragma unroll
        for (int off = 32; off >= 1; off >>= 1) {
            s1 += __shfl_xor(s1, off);
            s2 += __shfl_xor(s2, off);
        }
        float m = s1 * (1.f / HD);
        float inv = rsqrtf(s2 * (1.f / HD) - m * m + EPS_);
        float o0 = (v0 - m) * inv * g0 + b0;
        float o1 = (v1 - m) * inv * g1 + b1;
        size_t off0 = (size_t)h * NTOKS * HD + lane;
        if (wid == 0) {
            qbb[off0] = f2b(o0 * SCALE2_);
            if (two) qbb[off0 + 64] = f2b(o1 * SCALE2_);
        } else if (wid == 1) {
            size_t kb = (size_t)h * NTOKS * KCH;
            kx[kb + lane] = f2b(o0);
            if (two) kx[kb + 64 + lane] = f2b(o1);
            kx[kb + 96 + lane] = 0;              // cls: no one-hot bias channels
        } else {
            vbb[off0] = f2b(o0);
            if (two) vbb[off0 + 64] = f2b(o1);
        }
        return;
    }

    const int ss = s - 1;
    const int t  = ss / 196;
    const int rm = ss % 196;
    const int y  = rm / 7;
    const int x0 = (rm % 7) * 4;

    // ---- stage this mat's slab: 11 rounds x 64 async16 chunks (648 real, clamped) ----
    #pragma unroll
    for (int r = 0; r < 11; ++r) {
        int cbase = r * 64;
        int c = cbase + lane; if (c > 647) c = 647;   // clamp src; dest goes to pad
        int rrxx = c / 12, ck = c - rrxx * 12;
        int rr = rrxx / 6, xx = rrxx - rr * 6;
        int tt = t + rr / 3 - 1; tt = tt < 0 ? 0 : (tt > T_ - 1 ? T_ - 1 : tt);
        int yy = y + rr % 3 - 1; yy = yy < 0 ? 0 : (yy > H_ - 1 ? H_ - 1 : yy);
        int xp = x0 - 1 + xx;    int xc = xp < 0 ? 0 : (xp > W_ - 1 ? W_ - 1 : xp);
        int tok = 1 + (tt * H_ + yy) * W_ + xc;
        const u16* src = qkvb + (size_t)tok * 576 + col0 + ck * 8;
        async16(src, sls + cbase * 8);
    }
    __syncthreads();

    const float* wslice = wT + wid * 2592;   // [27][96]
    float v0a[4] = {0,0,0,0}, v1a[4] = {0,0,0,0};

    #pragma unroll
    for (int dt = -1; dt <= 1; ++dt) {
        int tt = t + dt; if (tt < 0 || tt >= T_) continue;
        #pragma unroll
        for (int dy = -1; dy <= 1; ++dy) {
            int yy = y + dy; if (yy < 0 || yy >= H_) continue;
            int wb = (dt + 1) * 9 + (dy + 1) * 3;
            int rr = (dt + 1) * 3 + (dy + 1);
            float wa[3], wbh[3];
            #pragma unroll
            for (int o = 0; o < 3; ++o) {
                wa[o]  = wslice[(wb + o) * 96 + lane];
                wbh[o] = two ? wslice[(wb + o) * 96 + 64 + lane] : 0.f;
            }
            #pragma unroll
            for (int i = 0; i < 6; ++i) {
                int xp = x0 - 1 + i;
                if (xp < 0 || xp >= W_) continue;    // wave-uniform guard
                const u16* rbase = sls + (rr * 6 + i) * 96;
                float r0 = b2f(rbase[lane]);
                float r1 = two ? b2f(rbase[64 + lane]) : 0.f;
                #pragma unroll
                for (int j = 0; j < 4; ++j) {
                    int o = i - j;
                    if (o >= 0 && o <= 2) {
                        v0a[j] += wa[o] * r0;
                        v1a[j] += wbh[o] * r1;
                    }
                }
            }
        }
    }

    #pragma unroll
    for (int j = 0; j < 4; ++j) {
        float s1 = v0a[j] + v1a[j];
        float s2 = v0a[j] * v0a[j] + v1a[j] * v1a[j];
        #pragma unroll
        for (int off = 32; off >= 1; off >>= 1) {
            s1 += __shfl_xor(s1, off);
            s2 += __shfl_xor(s2, off);
        }
        float m = s1 * (1.f / HD);
        float inv = rsqrtf(s2 * (1.f / HD) - m * m + EPS_);
        float o0 = (v0a[j] - m) * inv * g0 + b0;
        float o1 = (v1a[j] - m) * inv * g1 + b1;
        int xj  = x0 + j;
        int tok = 1 + (t * H_ + y) * W_ + xj;
        size_t off0 = ((size_t)h * NTOKS + tok) * HD + lane;
        if (wid == 0) {
            qbb[off0] = f2b(o0 * SCALE2_);
            qls[j][lane] = o0;
            if (two) { qbb[off0 + 64] = f2b(o1 * SCALE2_); qls[j][64 + lane] = o1; }
        } else if (wid == 1) {
            size_t kb = ((size_t)h * NTOKS + tok) * KCH;
            kx[kb + lane] = f2b(o0);
            if (two) kx[kb + 64 + lane] = f2b(o1);
            // one-hot bias channels (96..159): kt=t, kh=y, kw=xj
            int match = (lane < 8) ? (lane == t) : (lane < 36) ? (lane - 8 == y) : (lane - 36 == xj);
            kx[kb + 96 + lane] = match ? (u16)0x3F80 : (u16)0;
        } else {
            vbb[off0] = f2b(o0);
            if (two) vbb[off0 + 64] = f2b(o1);
        }
    }

    if (wid == 0) {   // rel-bias tail (same wave that wrote qls — no barrier needed)
        int tq = lane;
        #pragma unroll
        for (int j = 0; j < 4; ++j) {
            int sp = (t * H_ + y) * W_ + x0 + j;   // tok-1
            const float* row;
            float* outp;
            if (tq < 8)       { row = rel_t + (size_t)(t - tq        + (T_ - 1)) * HD; outp = bt + ((size_t)h*NSP + sp)*8  + tq;      }
            else if (tq < 36) { row = rel_h + (size_t)(y - (tq - 8)  + (H_ - 1)) * HD; outp = bh + ((size_t)h*NSP + sp)*28 + (tq-8);  }
            else              { row = rel_w + (size_t)(x0 + j - (tq - 36) + (W_ - 1)) * HD; outp = bw + ((size_t)h*NSP + sp)*28 + (tq-36); }
            const float4* r4 = (const float4*)row;
            const float4* q4 = (const float4*)qls[j];
            float acc = 0.f;
            #pragma unroll
            for (int i = 0; i < 24; ++i) {
                float4 a = q4[i], b = r4[i];
                acc += a.x*b.x + a.y*b.y + a.z*b.z + a.w*b.w;
            }
            *outp = acc;
        }
    }
}

// ------------- Kernel 2b: transpose V to [h][c][tok] (coalesced, proven cheap) -------
__global__ __launch_bounds__(256) void vtrans(
    const u16* __restrict__ vbb, u16* __restrict__ vbT)
{
    __shared__ u16 tls[128][104];
    int h  = blockIdx.y;
    int t0 = blockIdx.x * 128;
    int tid = threadIdx.x;
    #pragma unroll
    for (int it = 0; it < 24; ++it) {           // 128*48 dwords
        int idx = tid + it * 256;
        int row = idx / 48, col = idx % 48;
        int tok = t0 + row; if (tok > NTOKS - 1) tok = NTOKS - 1;
        *(u32*)&tls[row][col*2] = *(const u32*)(vbb + ((size_t)h * NTOKS + tok) * HD + col*2);
    }
    __syncthreads();
    #pragma unroll
    for (int it = 0; it < 24; ++it) {           // 96*64 dwords
        int idx = tid + it * 256;
        int c = idx / 64, tp = idx % 64;
        u32 lo = tls[tp*2][c], hi = tls[tp*2+1][c];
        *(u32*)(vbT + ((size_t)h * HD + c) * VT_LD + t0 + tp*2) = lo | (hi << 16);
    }
}

// ------------- Kernel 4: MFMA flash attention v9 (proven R9: <=67us) -----------------
__global__ __launch_bounds__(512, 4) void attn_mfma4(
    const u16* __restrict__ qbb, const u16* __restrict__ kx,
    const u16* __restrict__ vbT,
    const float* __restrict__ btp, const float* __restrict__ bhp,
    const float* __restrict__ bwp,
    u16* __restrict__ pO, float* __restrict__ pl)
{
    __shared__ __align__(16) u16 kls[2][20 * 512];  // 40 KB
    __shared__ __align__(16) u16 vls[2][12 * 512];  // 24 KB
    __shared__ __align__(16) u16 pls[128 * 64];     // 16 KB (XOR-swizzled)

    const int g     = blockIdx.x % (HEADS * NSPL);
    const int qb    = blockIdx.x / (HEADS * NSPL);
    const int h     = g / NSPL;
    const int split = g % NSPL;
    const int q0    = qb * QT;
    const int tid   = threadIdx.x;
    const int w     = tid >> 6;          // 0..7
    const int lane  = tid & 63;
    const int quad  = lane >> 4;
    const int l16   = lane & 15;

    const int t0 = split * SPT;
    const int t1 = (t0 + SPT < NTILES_TOT) ? t0 + SPT : NTILES_TOT;

    // 32 staging chunks (20 K + 12 V) over 8 waves, 4 each; wave-uniform branch.
    auto stage = [&](int buf, int tile) {
        int kb0 = tile * KT;
        int key = kb0 + lane; if (key > NTOKS - 1) key = NTOKS - 1;
        const u16* gbase = kx + ((size_t)h * NTOKS + key) * KCH;
        #pragma unroll
        for (int i = 0; i < 4; ++i) {
            int c = w * 4 + i;
            if (c < 20) {
                int c5 = c >> 2, qd = c & 3;
                async16(gbase + c5 * 32 + qd * 8, kls[buf] + c * 512);
            } else {
                int CH2 = c - 20;
                int E = CH2 * 64 + lane;
                int kcq = E / 96, n = E - kcq * 96;
                int kc = kcq >> 2, qd = kcq & 3;
                const u16* src = vbT + ((size_t)h * HD + n) * VT_LD + kb0 + kc * 32 + qd * 8;
                async16(src, vls[buf] + CH2 * 512);
            }
        }
    };

    stage(0, t0);

    bf16x8 aq[5];
    {
        int tokc = q0 + w * 16 + l16;
        int tq = tokc > NTOKS - 1 ? NTOKS - 1 : tokc;
        const u16* qrow = qbb + ((size_t)h * NTOKS + tq) * HD;
        #pragma unroll
        for (int cc = 0; cc < 3; ++cc)
            aq[cc] = *(const bf16x8*)(qrow + cc * 32 + quad * 8);
        bool has = (tokc >= 1 && tokc < NTOKS);
        int sp = tokc - 1;
        #pragma unroll
        for (int cc = 3; cc < 5; ++cc) {
            bf16x8 tf;
            #pragma unroll
            for (int j = 0; j < 8; ++j) {
                int kk = (cc - 3) * 32 + quad * 8 + j;
                float v = 0.f;
                if (has) {
                    if (kk < 8)       v = btp[((size_t)h * NSP + sp) * 8  + kk];
                    else if (kk < 36) v = bhp[((size_t)h * NSP + sp) * 28 + (kk - 8)];
                    else              v = bwp[((size_t)h * NSP + sp) * 28 + (kk - 36)];
                }
                tf[j] = (short)f2b(v * LOG2E_);   // exp2-domain bias
            }
            aq[cc] = tf;
        }
    }

    f32x4 accO[6];
    #pragma unroll
    for (int nt = 0; nt < 6; ++nt) accO[nt] = (f32x4){0,0,0,0};
    float psum[4] = {0.f, 0.f, 0.f, 0.f};

    for (int tile = t0; tile < t1; ++tile) {
        const int cur = (tile - t0) & 1;
        __syncthreads();
        if (tile + 1 < t1) stage(cur ^ 1, tile + 1);
        const int kb0 = tile * KT;
        const u16* kcur = kls[cur];
        const u16* vcur = vls[cur];
        f32x4 sacc[4];
        #pragma unroll
        for (int nt = 0; nt < 4; ++nt) sacc[nt] = (f32x4){0,0,0,0};
        __builtin_amdgcn_s_setprio(1);
        #pragma unroll
        for (int cc = 0; cc < 5; ++cc) {
            #pragma unroll
            for (int nt = 0; nt < 4; ++nt) {
                bf16x8 bk = *(const bf16x8*)(kcur + (((cc * 4 + quad) * 64) + nt * 16 + l16) * 8);
                sacc[nt] = __builtin_amdgcn_mfma_f32_16x16x32_bf16(aq[cc], bk, sacc[nt], 0, 0, 0);
            }
        }
        __builtin_amdgcn_s_setprio(0);
        const int r0 = w * 16 + quad * 4;
        #pragma unroll
        for (int nt = 0; nt < 4; ++nt) {
            int keyg = kb0 + nt * 16 + l16;
            bool ok = keyg < NTOKS;
            float e0, e1, e2, e3;
            asm("v_exp_f32 %0, %1" : "=v"(e0) : "v"(sacc[nt][0]));
            asm("v_exp_f32 %0, %1" : "=v"(e1) : "v"(sacc[nt][1]));
            asm("v_exp_f32 %0, %1" : "=v"(e2) : "v"(sacc[nt][2]));
            asm("v_exp_f32 %0, %1" : "=v"(e3) : "v"(sacc[nt][3]));
            e0 = ok ? e0 : 0.f; e1 = ok ? e1 : 0.f;
            e2 = ok ? e2 : 0.f; e3 = ok ? e3 : 0.f;
            psum[0] += e0; psum[1] += e1; psum[2] += e2; psum[3] += e3;
            u32 p01, p23;
            asm("v_cvt_pk_bf16_f32 %0, %1, %2" : "=v"(p01) : "v"(e0), "v"(e1));
            asm("v_cvt_pk_bf16_f32 %0, %1, %2" : "=v"(p23) : "v"(e2), "v"(e3));
            const int colb = nt * 32 + l16 * 2;
            *(u16*)((char*)pls + (r0+0) * 128 + (colb ^ (((r0+0) & 7) << 4))) = (u16)p01;
            *(u16*)((char*)pls + (r0+1) * 128 + (colb ^ (((r0+1) & 7) << 4))) = (u16)(p01 >> 16);
            *(u16*)((char*)pls + (r0+2) * 128 + (colb ^ (((r0+2) & 7) << 4))) = (u16)p23;
            *(u16*)((char*)pls + (r0+3) * 128 + (colb ^ (((r0+3) & 7) << 4))) = (u16)(p23 >> 16);
        }
        __builtin_amdgcn_s_setprio(1);
        #pragma unroll
        for (int kc = 0; kc < 2; ++kc) {
            int prow = w * 16 + l16;
            int pbyte = prow * 128 + ((kc * 64 + quad * 16) ^ ((prow & 7) << 4));
            bf16x8 ap = *(const bf16x8*)((const char*)pls + pbyte);
            #pragma unroll
            for (int nt = 0; nt < 6; ++nt) {
                bf16x8 bv = *(const bf16x8*)(vcur + (((kc * 4 + quad) * 96) + nt * 16 + l16) * 8);
                accO[nt] = __builtin_amdgcn_mfma_f32_16x16x32_bf16(ap, bv, accO[nt], 0, 0, 0);
            }
        }
        __builtin_amdgcn_s_setprio(0);
    }

    #pragma unroll
    for (int off = 1; off < 16; off <<= 1) {
        #pragma unroll
        for (int rr = 0; rr < 4; ++rr)
            psum[rr] += __shfl_xor(psum[rr], off);
    }
    const int sh = split * HEADS + h;
    if (l16 == 0) {
        #pragma unroll
        for (int rr = 0; rr < 4; ++rr) {
            int tok = q0 + w * 16 + quad * 4 + rr;
            if (tok < NTOKS)
                pl[(size_t)sh * NTOKS + tok] = psum[rr];
        }
    }
    #pragma unroll
    for (int rr = 0; rr < 4; ++rr) {
        int tok = q0 + w * 16 + quad * 4 + rr;
        if (tok >= NTOKS) continue;
        #pragma unroll
        for (int nt = 0; nt < 6; ++nt)
            pO[((size_t)sh * NTOKS + tok) * HD + nt * 16 + l16] = f2b(accO[nt][rr]);
    }
}

// ------- Kernel 4b: combine bf16 k-split partials + bf16 residual -> bf16 pre -------
__global__ __launch_bounds__(256) void combine(
    const u16* __restrict__ pO, const float* __restrict__ pl,
    const u16* __restrict__ qbb, u16* __restrict__ preb)
{
    int i = blockIdx.x * 256 + threadIdx.x;   // pair index: (tok, channel-pair)
    const int NP = NTOKS * 96;
    if (i >= NP) return;
    int tok = i / 96, dp = i - tok * 96;
    int d0 = dp * 2;
    int hh = d0 / HD, c0 = d0 - hh * HD;
    float l = 0.f, o0 = 0.f, o1 = 0.f;
    #pragma unroll
    for (int s = 0; s < NSPL; ++s) {
        l += pl[(size_t)(s * HEADS + hh) * NTOKS + tok];
        u32 pr = *(const u32*)(pO + ((size_t)(s * HEADS + hh) * NTOKS + tok) * HD + c0);
        o0 += b2f((u16)(pr & 0xffffu));
        o1 += b2f((u16)(pr >> 16));
    }
    float v0 = o0 / l, v1 = o1 / l;
    if (tok >= 1) {
        u32 qr = *(const u32*)(qbb + ((size_t)hh * NTOKS + tok) * HD + c0);
        v0 += b2f((u16)(qr & 0xffffu)) * RINV_;
        v1 += b2f((u16)(qr >> 16)) * RINV_;
    }
    u32 pack = (u32)f2b(v0) | ((u32)f2b(v1) << 16);
    *(u32*)(preb + (size_t)tok * DIM + d0) = pack;
}

extern "C" void kernel_launch(void* const* d_in, const int* in_sizes, int n_in,
                              void* d_out, int out_size, void* d_ws, size_t ws_size,
                              hipStream_t stream) {
    (void)in_sizes; (void)n_in; (void)out_size; (void)ws_size;
    const float* x      = (const float*)d_in[0];
    const float* qkv_w  = (const float*)d_in[1];
    const float* qkv_b  = (const float*)d_in[2];
    const float* proj_w = (const float*)d_in[3];
    const float* proj_b = (const float*)d_in[4];
    const float* pool_q = (const float*)d_in[5];
    const float* pool_k = (const float*)d_in[6];
    const float* pool_v = (const float*)d_in[7];
    const float* gq     = (const float*)d_in[8];
    const float* bq     = (const float*)d_in[9];
    const float* gk     = (const float*)d_in[10];
    const float* bk     = (const float*)d_in[11];
    const float* gv     = (const float*)d_in[12];
    const float* bv     = (const float*)d_in[13];
    const float* rel_h  = (const float*)d_in[14];
    const float* rel_w  = (const float*)d_in[15];
    const float* rel_t  = (const float*)d_in[16];

    char* p = (char*)d_ws;
    auto alloc = [&](size_t bytes) -> void* {
        void* r = (void*)p; p += (bytes + 255) & ~(size_t)255; return r;
    };
    u16*   qkvb = (u16*) alloc((size_t)NTOKS * 576 * 2);
    u16*   qbb = (u16*)  alloc((size_t)HEADS * NTOKS * HD * 2);
    u16*   kxb = (u16*)  alloc((size_t)HEADS * NTOKS * KCH * 2);
    u16*   vbb = (u16*)  alloc((size_t)HEADS * NTOKS * HD * 2);
    u16*   vbT = (u16*)  alloc((size_t)HEADS * HD * VT_LD * 2);
    float* bt  = (float*)alloc((size_t)HEADS * NSP * 8 * 4);
    float* bh  = (float*)alloc((size_t)HEADS * NSP * 28 * 4);
    float* bw  = (float*)alloc((size_t)HEADS * NSP * 28 * 4);
    u16*   pO  = (u16*)  alloc((size_t)NSPL * HEADS * NTOKS * HD * 2);
    float* pl  = (float*)alloc((size_t)NSPL * HEADS * NTOKS * 4);
    u16*   xb  = (u16*)  alloc((size_t)NTOKS * DIM * 2);
    u16*   qwb = (u16*)  alloc((size_t)576 * DIM * 2);
    u16*   pwb = (u16*)  alloc((size_t)DIM * DIM * 2);
    u16*   preb= (u16*)  alloc((size_t)NTOKS * DIM * 2);
    float* wT  = (float*)alloc((size_t)3 * 27 * 96 * 4);

    const int nx = NTOKS * DIM, nqw = 576 * DIM, npw = DIM * DIM;
    cvt_bf16<<<1024, 256, 0, stream>>>(x, xb, nx, qkv_w, qwb, nqw, proj_w, pwb, npw,
                                       pool_q, pool_k, pool_v, wT);
    gemm_bf16<<<dim3(99, 9), 256, 0, stream>>>(xb, qwb, qkv_b, nullptr, qkvb, NTOKS, 576);
    pool_ln9<<<dim3(NSTRIP, 3, HEADS), 64, 0, stream>>>(
        qkvb, wT, gq, bq, gk, bk, gv, bv,
        rel_h, rel_w, rel_t, qbb, kxb, vbb, bt, bh, bw);
    vtrans<<<dim3((NTOKS + 127) / 128, HEADS), 256, 0, stream>>>(vbb, vbT);
    attn_mfma4<<<QB * HEADS * NSPL, 512, 0, stream>>>(qbb, kxb, vbT, bt, bh, bw, pO, pl);
    combine<<<(NTOKS * 96 + 255) / 256, 256, 0, stream>>>(pO, pl, qbb, preb);
    gemm_bf16<<<dim3(99, 3), 256, 0, stream>>>(preb, pwb, proj_b, (float*)d_out, nullptr, NTOKS, 192);
}

// Round 13
// 250.381 us; speedup vs baseline: 1.0243x; 1.0243x over previous
//
#include <hip/hip_runtime.h>

#define T_    8
#define H_    28
#define W_    28
#define NSP   6272      // T*H*W
#define NTOKS 6273
#define DIM   192
#define HEADS 2
#define HD    96
#define SCALE2_ 0.14724441f             // 96^-0.5 * log2(e)  (exp -> exp2 domain)
#define RINV_   6.7914276f              // sqrt(96) * ln(2)   (residual undo of SCALE2_)
#define LOG2E_  1.4426950408889634f
#define EPS_  1e-5f

#define QT    128                       // q-rows per block (8 waves x 16)
#define KT    64
#define QB    50                        // ceil(6273/128)
#define NTILES_TOT 99
#define NSPL  5                         // 50*2*5 = 500 blocks <= 512 capacity => ONE round
#define SPT   20                        // ceil(99/5) tiles per split
#define KCH   160                       // extended K channels (96 + 64 one-hot)
#define VT_LD 6400                      // padded vbT row length (tokens)
#define NSTRIP 1569                     // 1 cls + 8*28*7 spatial strips (4 x-tokens each)

using bf16x8 = __attribute__((ext_vector_type(8))) short;
using f32x4  = __attribute__((ext_vector_type(4))) float;
using u32x4  = __attribute__((ext_vector_type(4))) unsigned int;
typedef unsigned short u16;
typedef unsigned int   u32;

__device__ __forceinline__ u16 f2b(float f) {   // fp32 -> bf16 bits, RNE
    u32 u = __builtin_bit_cast(u32, f);
    u += 0x7fffu + ((u >> 16) & 1u);
    return (u16)(u >> 16);
}
__device__ __forceinline__ float b2f(u16 v) {
    u32 u = ((u32)v) << 16;
    return __builtin_bit_cast(float, u);
}

// async global->LDS 16B: LDS dest is wave-uniform base + lane*16 (m104)
__device__ __forceinline__ void async16(const void* g, void* l) {
    __builtin_amdgcn_global_load_lds(
        (const __attribute__((address_space(1))) u32*)g,
        (__attribute__((address_space(3))) u32*)l, 16, 0, 0);
}

// pack 8 f32 -> bf16x8 (as u32x4)
__device__ __forceinline__ u32x4 pack8(const float* a) {
    u32x4 v;
    v[0] = (u32)f2b(a[0]) | ((u32)f2b(a[1]) << 16);
    v[1] = (u32)f2b(a[2]) | ((u32)f2b(a[3]) << 16);
    v[2] = (u32)f2b(a[4]) | ((u32)f2b(a[5]) << 16);
    v[3] = (u32)f2b(a[6]) | ((u32)f2b(a[7]) << 16);
    return v;
}

// ------ Kernel 1: GEMM with in-staging f32->bf16 convert (cvt kernel eliminated) -----
// OUT[m][n] = sum_k A[m][k]*W[n][k] + bias[n]. W always f32 (qkv_w/proj_w direct).
// A: AF32=1 -> f32 source (x); AF32=0 -> bf16 source (preb) via global_load_lds.
// QKV instance carries 9 extra blocks (blockIdx.x==99) that transpose the pool
// weights into wT (read by pool_ln6 in the NEXT kernel — no intra-kernel dependency).
template<int AF32>
__global__ __launch_bounds__(256, 3) void gemm_any(
    const void* __restrict__ Ap, const float* __restrict__ Wf,
    const float* __restrict__ bias, float* __restrict__ outf,
    u16* __restrict__ outb, int M, int ldo,
    const float* __restrict__ wq, const float* __restrict__ wk,
    const float* __restrict__ wv, float* __restrict__ wT)
{
    __shared__ __align__(16) u16 als[24 * 512];
    __shared__ __align__(16) u16 wls[24 * 512];
    if (wT && blockIdx.x == 99) {       // wT transpose rider blocks (QKV grid only)
        int j0 = blockIdx.y * 864;
        for (int r = threadIdx.x; r < 864; r += 256) {
            int j = j0 + r;                  // which*2592 + widx*96 + c
            int which = j / 2592, rem = j % 2592;
            int widx = rem / 96, c = rem % 96;
            const float* src = which == 0 ? wq : (which == 1 ? wk : wv);
            wT[j] = src[c * 27 + widx];
        }
        return;
    }
    const int m0 = blockIdx.x * 64, n0 = blockIdx.y * 64;
    const int tid  = threadIdx.x;
    const int w    = tid >> 6;
    const int lane = tid & 63;
    const int quad = lane >> 4;
    const int l16  = lane & 15;
    {
        int m = m0 + lane; if (m > M - 1) m = M - 1;
        const float* wb = Wf + (size_t)(n0 + lane) * 192;
        if (AF32) {
            const float* ab = (const float*)Ap + (size_t)m * 192;
            #pragma unroll
            for (int i = 0; i < 6; ++i) {
                int g = w * 6 + i;          // channels g*8..g*8+7
                float av[8], wv8[8];
                *(f32x4*)(av)     = *(const f32x4*)(ab + g * 8);
                *(f32x4*)(av + 4) = *(const f32x4*)(ab + g * 8 + 4);
                *(f32x4*)(wv8)     = *(const f32x4*)(wb + g * 8);
                *(f32x4*)(wv8 + 4) = *(const f32x4*)(wb + g * 8 + 4);
                *(u32x4*)(als + g * 512 + lane * 8) = pack8(av);
                *(u32x4*)(wls + g * 512 + lane * 8) = pack8(wv8);
            }
        } else {
            const u16* ab = (const u16*)Ap + (size_t)m * 192;
            #pragma unroll
            for (int i = 0; i < 6; ++i) {
                int g = w * 6 + i;
                async16(ab + g * 8, als + g * 512);
                float wv8[8];
                *(f32x4*)(wv8)     = *(const f32x4*)(wb + g * 8);
                *(f32x4*)(wv8 + 4) = *(const f32x4*)(wb + g * 8 + 4);
                *(u32x4*)(wls + g * 512 + lane * 8) = pack8(wv8);
            }
        }
    }
    __syncthreads();
    f32x4 acc[4];
    #pragma unroll
    for (int mt = 0; mt < 4; ++mt) acc[mt] = (f32x4){0,0,0,0};
    #pragma unroll
    for (int cc = 0; cc < 6; ++cc) {
        bf16x8 bf = *(const bf16x8*)(wls + (((cc * 4 + quad) * 64) + w * 16 + l16) * 8);
        #pragma unroll
        for (int mt = 0; mt < 4; ++mt) {
            bf16x8 af = *(const bf16x8*)(als + (((cc * 4 + quad) * 64) + mt * 16 + l16) * 8);
            acc[mt] = __builtin_amdgcn_mfma_f32_16x16x32_bf16(af, bf, acc[mt], 0, 0, 0);
        }
    }
    float bj = bias[n0 + w * 16 + l16];
    #pragma unroll
    for (int mt = 0; mt < 4; ++mt) {
        #pragma unroll
        for (int rr = 0; rr < 4; ++rr) {
            int row = m0 + mt * 16 + quad * 4 + rr;
            if (row < M) {
                float v = acc[mt][rr] + bj;
                size_t off = (size_t)row * ldo + n0 + w * 16 + l16;
                if (outb) outb[off] = f2b(v);
                else      outf[off] = v;
            }
        }
    }
}

// ------------- Kernel 2: pool+LN v6 (R9-exact, proven 67.0us) ------------------------
__global__ __launch_bounds__(192) void pool_ln6(
    const u16* __restrict__ qkvb, const float* __restrict__ wT,
    const float* __restrict__ gq, const float* __restrict__ bq,
    const float* __restrict__ gk, const float* __restrict__ bk,
    const float* __restrict__ gv, const float* __restrict__ bv,
    const float* __restrict__ rel_h, const float* __restrict__ rel_w,
    const float* __restrict__ rel_t,
    u16* __restrict__ qbb, u16* __restrict__ kx, u16* __restrict__ vbb,
    float* __restrict__ bt, float* __restrict__ bh, float* __restrict__ bw)
{
    // sls[(rr*6+xx)*3 + wseg][96]: rr=(dt+1)*3+(dy+1), xx=0..5, wseg=q/k/v.
    // 1944 16B-chunks padded to 1984 (31744 B).
    __shared__ __align__(16) u16 sls[15872];
    __shared__ __align__(16) float qls[4][96];
    const int h   = blockIdx.x / NSTRIP;
    const int s   = blockIdx.x % NSTRIP;
    const int wid  = threadIdx.x / 64;   // which: 0=q 1=k 2=v
    const int lane = threadIdx.x & 63;
    const bool two = (lane < 32);

    const float* gg = wid == 0 ? gq : (wid == 1 ? gk : gv);
    const float* bb = wid == 0 ? bq : (wid == 1 ? bk : bv);
    const float g0 = gg[lane], b0 = bb[lane];
    const float g1 = two ? gg[64 + lane] : 0.f;
    const float b1 = two ? bb[64 + lane] : 0.f;
    const int col0 = wid * DIM + h * HD;

    if (s == 0) {
        float v0 = b2f(qkvb[col0 + lane]);
        float v1 = two ? b2f(qkvb[col0 + 64 + lane]) : 0.f;
        float s1 = v0 + v1, s2 = v0 * v0 + v1 * v1;
        #pragma unroll
        for (int off = 32; off >= 1; off >>= 1) {
            s1 += __shfl_xor(s1, off);
            s2 += __shfl_xor(s2, off);
        }
        float m = s1 * (1.f / HD);
        float inv = rsqrtf(s2 * (1.f / HD) - m * m + EPS_);
        float o0 = (v0 - m) * inv * g0 + b0;
        float o1 = (v1 - m) * inv * g1 + b1;
        size_t off0 = (size_t)h * NTOKS * HD + lane;
        if (wid == 0) {
            qbb[off0] = f2b(o0 * SCALE2_);
            if (two) qbb[off0 + 64] = f2b(o1 * SCALE2_);
        } else if (wid == 1) {
            size_t kb = (size_t)h * NTOKS * KCH;
            kx[kb + lane] = f2b(o0);
            if (two) kx[kb + 64 + lane] = f2b(o1);
            kx[kb + 96 + lane] = 0;              // cls: no one-hot bias channels
        } else {
            vbb[off0] = f2b(o0);
            if (two) vbb[off0 + 64] = f2b(o1);
        }
        return;
    }

    const int ss = s - 1;
    const int t  = ss / 196;
    const int rm = ss % 196;
    const int y  = rm / 7;
    const int x0 = (rm % 7) * 4;

    // ---- stage the input slab: 31 wave-rounds of 64 async16 chunks over 3 waves ----
    for (int r = wid; r < 31; r += 3) {
        int cbase = r * 64;
        int c = cbase + lane; if (c > 1943) c = 1943;   // clamp src; dest goes to pad
        int rrxx = c / 36, rem = c - rrxx * 36;
        int wseg = rem / 12, ck = rem - wseg * 12;
        int rr = rrxx / 6, xx = rrxx - rr * 6;
        int tt = t + rr / 3 - 1; tt = tt < 0 ? 0 : (tt > T_ - 1 ? T_ - 1 : tt);
        int yy = y + rr % 3 - 1; yy = yy < 0 ? 0 : (yy > H_ - 1 ? H_ - 1 : yy);
        int xp = x0 - 1 + xx;    int xc = xp < 0 ? 0 : (xp > W_ - 1 ? W_ - 1 : xp);
        int tok = 1 + (tt * H_ + yy) * W_ + xc;
        const u16* src = qkvb + (size_t)tok * 576 + wseg * DIM + h * HD + ck * 8;
        async16(src, sls + cbase * 8);
    }
    __syncthreads();

    const float* wslice = wT + wid * 2592;   // [27][96]
    float v0a[4] = {0,0,0,0}, v1a[4] = {0,0,0,0};

    #pragma unroll
    for (int dt = -1; dt <= 1; ++dt) {
        int tt = t + dt; if (tt < 0 || tt >= T_) continue;
        #pragma unroll
        for (int dy = -1; dy <= 1; ++dy) {
            int yy = y + dy; if (yy < 0 || yy >= H_) continue;
            int wb = (dt + 1) * 9 + (dy + 1) * 3;
            int rr = (dt + 1) * 3 + (dy + 1);
            float wa[3], wbh[3];
            #pragma unroll
            for (int o = 0; o < 3; ++o) {
                wa[o]  = wslice[(wb + o) * 96 + lane];
                wbh[o] = two ? wslice[(wb + o) * 96 + 64 + lane] : 0.f;
            }
            #pragma unroll
            for (int i = 0; i < 6; ++i) {
                int xp = x0 - 1 + i;
                if (xp < 0 || xp >= W_) continue;    // wave-uniform guard
                const u16* rbase = sls + (rr * 18 + i * 3 + wid) * 96;
                float r0 = b2f(rbase[lane]);
                float r1 = two ? b2f(rbase[64 + lane]) : 0.f;
                #pragma unroll
                for (int j = 0; j < 4; ++j) {
                    int o = i - j;
                    if (o >= 0 && o <= 2) {
                        v0a[j] += wa[o] * r0;
                        v1a[j] += wbh[o] * r1;
                    }
                }
            }
        }
    }

    #pragma unroll
    for (int j = 0; j < 4; ++j) {
        float s1 = v0a[j] + v1a[j];
        float s2 = v0a[j] * v0a[j] + v1a[j] * v1a[j];
        #pragma unroll
        for (int off = 32; off >= 1; off >>= 1) {
            s1 += __shfl_xor(s1, off);
            s2 += __shfl_xor(s2, off);
        }
        float m = s1 * (1.f / HD);
        float inv = rsqrtf(s2 * (1.f / HD) - m * m + EPS_);
        float o0 = (v0a[j] - m) * inv * g0 + b0;
        float o1 = (v1a[j] - m) * inv * g1 + b1;
        int xj  = x0 + j;
        int tok = 1 + (t * H_ + y) * W_ + xj;
        size_t off0 = ((size_t)h * NTOKS + tok) * HD + lane;
        if (wid == 0) {
            qbb[off0] = f2b(o0 * SCALE2_);
            qls[j][lane] = o0;
            if (two) { qbb[off0 + 64] = f2b(o1 * SCALE2_); qls[j][64 + lane] = o1; }
        } else if (wid == 1) {
            size_t kb = ((size_t)h * NTOKS + tok) * KCH;
            kx[kb + lane] = f2b(o0);
            if (two) kx[kb + 64 + lane] = f2b(o1);
            // one-hot bias channels (96..159): kt=t, kh=y, kw=xj
            int match = (lane < 8) ? (lane == t) : (lane < 36) ? (lane - 8 == y) : (lane - 36 == xj);
            kx[kb + 96 + lane] = match ? (u16)0x3F80 : (u16)0;
        } else {
            vbb[off0] = f2b(o0);
            if (two) vbb[off0 + 64] = f2b(o1);
        }
    }

    if (threadIdx.x < 64) {
        int tq = threadIdx.x;
        #pragma unroll
        for (int j = 0; j < 4; ++j) {
            int sp = (t * H_ + y) * W_ + x0 + j;   // tok-1
            const float* row;
            float* outp;
            if (tq < 8)       { row = rel_t + (size_t)(t - tq        + (T_ - 1)) * HD; outp = bt + ((size_t)h*NSP + sp)*8  + tq;      }
            else if (tq < 36) { row = rel_h + (size_t)(y - (tq - 8)  + (H_ - 1)) * HD; outp = bh + ((size_t)h*NSP + sp)*28 + (tq-8);  }
            else              { row = rel_w + (size_t)(x0 + j - (tq - 36) + (W_ - 1)) * HD; outp = bw + ((size_t)h*NSP + sp)*28 + (tq-36); }
            const float4* r4 = (const float4*)row;
            const float4* q4 = (const float4*)qls[j];
            float acc = 0.f;
            #pragma unroll
            for (int i = 0; i < 24; ++i) {
                float4 a = q4[i], b = r4[i];
                acc += a.x*b.x + a.y*b.y + a.z*b.z + a.w*b.w;
            }
            *outp = acc;
        }
    }
}

// ------------- Kernel 2b: transpose V to [h][c][tok] (coalesced, proven cheap) -------
__global__ __launch_bounds__(256) void vtrans(
    const u16* __restrict__ vbb, u16* __restrict__ vbT)
{
    __shared__ u16 tls[128][104];
    int h  = blockIdx.y;
    int t0 = blockIdx.x * 128;
    int tid = threadIdx.x;
    #pragma unroll
    for (int it = 0; it < 24; ++it) {           // 128*48 dwords
        int idx = tid + it * 256;
        int row = idx / 48, col = idx % 48;
        int tok = t0 + row; if (tok > NTOKS - 1) tok = NTOKS - 1;
        *(u32*)&tls[row][col*2] = *(const u32*)(vbb + ((size_t)h * NTOKS + tok) * HD + col*2);
    }
    __syncthreads();
    #pragma unroll
    for (int it = 0; it < 24; ++it) {           // 96*64 dwords
        int idx = tid + it * 256;
        int c = idx / 64, tp = idx % 64;
        u32 lo = tls[tp*2][c], hi = tls[tp*2+1][c];
        *(u32*)(vbT + ((size_t)h * HD + c) * VT_LD + t0 + tp*2) = lo | (hi << 16);
    }
}

// ------------- Kernel 4: MFMA flash attention v9 (proven R9) -------------------------
__global__ __launch_bounds__(512, 4) void attn_mfma4(
    const u16* __restrict__ qbb, const u16* __restrict__ kx,
    const u16* __restrict__ vbT,
    const float* __restrict__ btp, const float* __restrict__ bhp,
    const float* __restrict__ bwp,
    u16* __restrict__ pO, float* __restrict__ pl)
{
    __shared__ __align__(16) u16 kls[2][20 * 512];  // 40 KB
    __shared__ __align__(16) u16 vls[2][12 * 512];  // 24 KB
    __shared__ __align__(16) u16 pls[128 * 64];     // 16 KB (XOR-swizzled)

    const int g     = blockIdx.x % (HEADS * NSPL);
    const int qb    = blockIdx.x / (HEADS * NSPL);
    const int h     = g / NSPL;
    const int split = g % NSPL;
    const int q0    = qb * QT;
    const int tid   = threadIdx.x;
    const int w     = tid >> 6;          // 0..7
    const int lane  = tid & 63;
    const int quad  = lane >> 4;
    const int l16   = lane & 15;

    const int t0 = split * SPT;
    const int t1 = (t0 + SPT < NTILES_TOT) ? t0 + SPT : NTILES_TOT;

    // 32 staging chunks (20 K + 12 V) over 8 waves, 4 each; wave-uniform branch.
    auto stage = [&](int buf, int tile) {
        int kb0 = tile * KT;
        int key = kb0 + lane; if (key > NTOKS - 1) key = NTOKS - 1;
        const u16* gbase = kx + ((size_t)h * NTOKS + key) * KCH;
        #pragma unroll
        for (int i = 0; i < 4; ++i) {
            int c = w * 4 + i;
            if (c < 20) {
                int c5 = c >> 2, qd = c & 3;
                async16(gbase + c5 * 32 + qd * 8, kls[buf] + c * 512);
            } else {
                int CH2 = c - 20;
                int E = CH2 * 64 + lane;
                int kcq = E / 96, n = E - kcq * 96;
                int kc = kcq >> 2, qd = kcq & 3;
                const u16* src = vbT + ((size_t)h * HD + n) * VT_LD + kb0 + kc * 32 + qd * 8;
                async16(src, vls[buf] + CH2 * 512);
            }
        }
    };

    stage(0, t0);

    bf16x8 aq[5];
    {
        int tokc = q0 + w * 16 + l16;
        int tq = tokc > NTOKS - 1 ? NTOKS - 1 : tokc;
        const u16* qrow = qbb + ((size_t)h * NTOKS + tq) * HD;
        #pragma unroll
        for (int cc = 0; cc < 3; ++cc)
            aq[cc] = *(const bf16x8*)(qrow + cc * 32 + quad * 8);
        bool has = (tokc >= 1 && tokc < NTOKS);
        int sp = tokc - 1;
        #pragma unroll
        for (int cc = 3; cc < 5; ++cc) {
            bf16x8 tf;
            #pragma unroll
            for (int j = 0; j < 8; ++j) {
                int kk = (cc - 3) * 32 + quad * 8 + j;
                float v = 0.f;
                if (has) {
                    if (kk < 8)       v = btp[((size_t)h * NSP + sp) * 8  + kk];
                    else if (kk < 36) v = bhp[((size_t)h * NSP + sp) * 28 + (kk - 8)];
                    else              v = bwp[((size_t)h * NSP + sp) * 28 + (kk - 36)];
                }
                tf[j] = (short)f2b(v * LOG2E_);   // exp2-domain bias
            }
            aq[cc] = tf;
        }
    }

    f32x4 accO[6];
    #pragma unroll
    for (int nt = 0; nt < 6; ++nt) accO[nt] = (f32x4){0,0,0,0};
    float psum[4] = {0.f, 0.f, 0.f, 0.f};

    for (int tile = t0; tile < t1; ++tile) {
        const int cur = (tile - t0) & 1;
        __syncthreads();
        if (tile + 1 < t1) stage(cur ^ 1, tile + 1);
        const int kb0 = tile * KT;
        const u16* kcur = kls[cur];
        const u16* vcur = vls[cur];
        f32x4 sacc[4];
        #pragma unroll
        for (int nt = 0; nt < 4; ++nt) sacc[nt] = (f32x4){0,0,0,0};
        __builtin_amdgcn_s_setprio(1);
        #pragma unroll
        for (int cc = 0; cc < 5; ++cc) {
            #pragma unroll
            for (int nt = 0; nt < 4; ++nt) {
                bf16x8 bk = *(const bf16x8*)(kcur + (((cc * 4 + quad) * 64) + nt * 16 + l16) * 8);
                sacc[nt] = __builtin_amdgcn_mfma_f32_16x16x32_bf16(aq[cc], bk, sacc[nt], 0, 0, 0);
            }
        }
        __builtin_amdgcn_s_setprio(0);
        const int r0 = w * 16 + quad * 4;
        #pragma unroll
        for (int nt = 0; nt < 4; ++nt) {
            int keyg = kb0 + nt * 16 + l16;
            bool ok = keyg < NTOKS;
            float e0, e1, e2, e3;
            asm("v_exp_f32 %0, %1" : "=v"(e0) : "v"(sacc[nt][0]));
            asm("v_exp_f32 %0, %1" : "=v"(e1) : "v"(sacc[nt][1]));
            asm("v_exp_f32 %0, %1" : "=v"(e2) : "v"(sacc[nt][2]));
            asm("v_exp_f32 %0, %1" : "=v"(e3) : "v"(sacc[nt][3]));
            e0 = ok ? e0 : 0.f; e1 = ok ? e1 : 0.f;
            e2 = ok ? e2 : 0.f; e3 = ok ? e3 : 0.f;
            psum[0] += e0; psum[1] += e1; psum[2] += e2; psum[3] += e3;
            u32 p01, p23;
            asm("v_cvt_pk_bf16_f32 %0, %1, %2" : "=v"(p01) : "v"(e0), "v"(e1));
            asm("v_cvt_pk_bf16_f32 %0, %1, %2" : "=v"(p23) : "v"(e2), "v"(e3));
            const int colb = nt * 32 + l16 * 2;
            *(u16*)((char*)pls + (r0+0) * 128 + (colb ^ (((r0+0) & 7) << 4))) = (u16)p01;
            *(u16*)((char*)pls + (r0+1) * 128 + (colb ^ (((r0+1) & 7) << 4))) = (u16)(p01 >> 16);
            *(u16*)((char*)pls + (r0+2) * 128 + (colb ^ (((r0+2) & 7) << 4))) = (u16)p23;
            *(u16*)((char*)pls + (r0+3) * 128 + (colb ^ (((r0+3) & 7) << 4))) = (u16)(p23 >> 16);
        }
        __builtin_amdgcn_s_setprio(1);
        #pragma unroll
        for (int kc = 0; kc < 2; ++kc) {
            int prow = w * 16 + l16;
            int pbyte = prow * 128 + ((kc * 64 + quad * 16) ^ ((prow & 7) << 4));
            bf16x8 ap = *(const bf16x8*)((const char*)pls + pbyte);
            #pragma unroll
            for (int nt = 0; nt < 6; ++nt) {
                bf16x8 bv = *(const bf16x8*)(vcur + (((kc * 4 + quad) * 96) + nt * 16 + l16) * 8);
                accO[nt] = __builtin_amdgcn_mfma_f32_16x16x32_bf16(ap, bv, accO[nt], 0, 0, 0);
            }
        }
        __builtin_amdgcn_s_setprio(0);
    }

    #pragma unroll
    for (int off = 1; off < 16; off <<= 1) {
        #pragma unroll
        for (int rr = 0; rr < 4; ++rr)
            psum[rr] += __shfl_xor(psum[rr], off);
    }
    const int sh = split * HEADS + h;
    if (l16 == 0) {
        #pragma unroll
        for (int rr = 0; rr < 4; ++rr) {
            int tok = q0 + w * 16 + quad * 4 + rr;
            if (tok < NTOKS)
                pl[(size_t)sh * NTOKS + tok] = psum[rr];
        }
    }
    #pragma unroll
    for (int rr = 0; rr < 4; ++rr) {
        int tok = q0 + w * 16 + quad * 4 + rr;
        if (tok >= NTOKS) continue;
        #pragma unroll
        for (int nt = 0; nt < 6; ++nt)
            pO[((size_t)sh * NTOKS + tok) * HD + nt * 16 + l16] = f2b(accO[nt][rr]);
    }
}

// ------- Kernel 4b: combine bf16 k-split partials + bf16 residual -> bf16 pre -------
__global__ __launch_bounds__(256) void combine(
    const u16* __restrict__ pO, const float* __restrict__ pl,
    const u16* __restrict__ qbb, u16* __restrict__ preb)
{
    int i = blockIdx.x * 256 + threadIdx.x;   // pair index: (tok, channel-pair)
    const int NP = NTOKS * 96;
    if (i >= NP) return;
    int tok = i / 96, dp = i - tok * 96;
    int d0 = dp * 2;
    int hh = d0 / HD, c0 = d0 - hh * HD;
    float l = 0.f, o0 = 0.f, o1 = 0.f;
    #pragma unroll
    for (int s = 0; s < NSPL; ++s) {
        l += pl[(size_t)(s * HEADS + hh) * NTOKS + tok];
        u32 pr = *(const u32*)(pO + ((size_t)(s * HEADS + hh) * NTOKS + tok) * HD + c0);
        o0 += b2f((u16)(pr & 0xffffu));
        o1 += b2f((u16)(pr >> 16));
    }
    float v0 = o0 / l, v1 = o1 / l;
    if (tok >= 1) {
        u32 qr = *(const u32*)(qbb + ((size_t)hh * NTOKS + tok) * HD + c0);
        v0 += b2f((u16)(qr & 0xffffu)) * RINV_;
        v1 += b2f((u16)(qr >> 16)) * RINV_;
    }
    u32 pack = (u32)f2b(v0) | ((u32)f2b(v1) << 16);
    *(u32*)(preb + (size_t)tok * DIM + d0) = pack;
}

extern "C" void kernel_launch(void* const* d_in, const int* in_sizes, int n_in,
                              void* d_out, int out_size, void* d_ws, size_t ws_size,
                              hipStream_t stream) {
    (void)in_sizes; (void)n_in; (void)out_size; (void)ws_size;
    const float* x      = (const float*)d_in[0];
    const float* qkv_w  = (const float*)d_in[1];
    const float* qkv_b  = (const float*)d_in[2];
    const float* proj_w = (const float*)d_in[3];
    const float* proj_b = (const float*)d_in[4];
    const float* pool_q = (const float*)d_in[5];
    const float* pool_k = (const float*)d_in[6];
    const float* pool_v = (const float*)d_in[7];
    const float* gq     = (const float*)d_in[8];
    const float* bq     = (const float*)d_in[9];
    const float* gk     = (const float*)d_in[10];
    const float* bk     = (const float*)d_in[11];
    const float* gv     = (const float*)d_in[12];
    const float* bv     = (const float*)d_in[13];
    const float* rel_h  = (const float*)d_in[14];
    const float* rel_w  = (const float*)d_in[15];
    const float* rel_t  = (const float*)d_in[16];

    char* p = (char*)d_ws;
    auto alloc = [&](size_t bytes) -> void* {
        void* r = (void*)p; p += (bytes + 255) & ~(size_t)255; return r;
    };
    u16*   qkvb = (u16*) alloc((size_t)NTOKS * 576 * 2);
    u16*   qbb = (u16*)  alloc((size_t)HEADS * NTOKS * HD * 2);
    u16*   kxb = (u16*)  alloc((size_t)HEADS * NTOKS * KCH * 2);
    u16*   vbb = (u16*)  alloc((size_t)HEADS * NTOKS * HD * 2);
    u16*   vbT = (u16*)  alloc((size_t)HEADS * HD * VT_LD * 2);
    float* bt  = (float*)alloc((size_t)HEADS * NSP * 8 * 4);
    float* bh  = (float*)alloc((size_t)HEADS * NSP * 28 * 4);
    float* bw  = (float*)alloc((size_t)HEADS * NSP * 28 * 4);
    u16*   pO  = (u16*)  alloc((size_t)NSPL * HEADS * NTOKS * HD * 2);
    float* pl  = (float*)alloc((size_t)NSPL * HEADS * NTOKS * 4);
    u16*   preb= (u16*)  alloc((size_t)NTOKS * DIM * 2);
    float* wT  = (float*)alloc((size_t)3 * 27 * 96 * 4);

    gemm_any<1><<<dim3(100, 9), 256, 0, stream>>>(
        x, qkv_w, qkv_b, nullptr, qkvb, NTOKS, 576,
        pool_q, pool_k, pool_v, wT);
    pool_ln6<<<HEADS * NSTRIP, 192, 0, stream>>>(
        qkvb, wT, gq, bq, gk, bk, gv, bv,
        rel_h, rel_w, rel_t, qbb, kxb, vbb, bt, bh, bw);
    vtrans<<<dim3((NTOKS + 127) / 128, HEADS), 256, 0, stream>>>(vbb, vbT);
    attn_mfma4<<<QB * HEADS * NSPL, 512, 0, stream>>>(qbb, kxb, vbT, bt, bh, bw, pO, pl);
    combine<<<(NTOKS * 96 + 255) / 256, 256, 0, stream>>>(pO, pl, qbb, preb);
    gemm_any<0><<<dim3(99, 3), 256, 0, stream>>>(
        preb, proj_w, proj_b, (float*)d_out, nullptr, NTOKS, 192,
        nullptr, nullptr, nullptr, nullptr);
}

// Round 15
// 243.838 us; speedup vs baseline: 1.0518x; 1.0268x over previous
//
#include <hip/hip_runtime.h>

#define T_    8
#define H_    28
#define W_    28
#define NSP   6272      // T*H*W
#define NTOKS 6273
#define DIM   192
#define HEADS 2
#define HD    96
#define SCALE2_ 0.14724441f             // 96^-0.5 * log2(e)  (exp -> exp2 domain)
#define RINV_   6.7914276f              // sqrt(96) * ln(2)   (residual undo of SCALE2_)
#define LOG2E_  1.4426950408889634f
#define EPS_  1e-5f

#define QT    256                       // q-rows per block (16 waves x 16)
#define KT    64
#define QB    25                        // ceil(6273/256)
#define NTILES_TOT 99
#define NSPL  5                         // 25*2*5 = 250 blocks, 1/CU => ONE round
#define SPT   20                        // ceil(99/5) tiles per split
#define KCH   160                       // extended K channels (96 + 64 one-hot)
#define VT_LD 6400                      // padded vbT row length (tokens)
#define NSTRIP 1569                     // 1 cls + 8*28*7 spatial strips (4 x-tokens each)

using bf16x8 = __attribute__((ext_vector_type(8))) short;
using f32x4  = __attribute__((ext_vector_type(4))) float;
typedef unsigned short u16;
typedef unsigned int   u32;

__device__ __forceinline__ u16 f2b(float f) {   // fp32 -> bf16 bits, RNE
    u32 u = __builtin_bit_cast(u32, f);
    u += 0x7fffu + ((u >> 16) & 1u);
    return (u16)(u >> 16);
}
__device__ __forceinline__ float b2f(u16 v) {
    u32 u = ((u32)v) << 16;
    return __builtin_bit_cast(float, u);
}

// async global->LDS 16B: LDS dest is wave-uniform base + lane*16 (m104)
__device__ __forceinline__ void async16(const void* g, void* l) {
    __builtin_amdgcn_global_load_lds(
        (const __attribute__((address_space(1))) u32*)g,
        (__attribute__((address_space(3))) u32*)l, 16, 0, 0);
}

// ------- Kernel 0: fp32 -> bf16 conversion (x, qkv_w, proj_w) + pool-weight transpose -------
__global__ __launch_bounds__(256) void cvt_bf16(
    const float* __restrict__ s0, u16* __restrict__ d0, int n0,
    const float* __restrict__ s1, u16* __restrict__ d1, int n1,
    const float* __restrict__ s2, u16* __restrict__ d2, int n2,
    const float* __restrict__ wq, const float* __restrict__ wk,
    const float* __restrict__ wv, float* __restrict__ wT)
{
    const int nw = 3 * 27 * 96;
    int tot = n0 + n1 + n2 + nw;
    for (int i = blockIdx.x * 256 + threadIdx.x; i < tot; i += gridDim.x * 256) {
        if (i < n0)                 d0[i] = f2b(s0[i]);
        else if (i < n0 + n1)       d1[i - n0] = f2b(s1[i - n0]);
        else if (i < n0 + n1 + n2)  d2[i - n0 - n1] = f2b(s2[i - n0 - n1]);
        else {
            int j = i - n0 - n1 - n2;       // which*2592 + widx*96 + c
            int which = j / 2592, r = j % 2592;
            int widx = r / 96, c = r % 96;
            const float* src = which == 0 ? wq : (which == 1 ? wk : wv);
            wT[j] = src[c * 27 + widx];
        }
    }
}

// ---------------- Kernel 1: OUT[m][n] = sum_k A[m][k]*W[n][k] + bias[n] (MFMA) --------
__global__ __launch_bounds__(256, 3) void gemm_bf16(
    const u16* __restrict__ A, const u16* __restrict__ Wt,
    const float* __restrict__ bias, float* __restrict__ outf,
    u16* __restrict__ outb, int M, int ldo)
{
    __shared__ __align__(16) u16 als[24 * 512];
    __shared__ __align__(16) u16 wls[24 * 512];
    const int m0 = blockIdx.x * 64, n0 = blockIdx.y * 64;
    const int tid  = threadIdx.x;
    const int w    = tid >> 6;
    const int lane = tid & 63;
    const int quad = lane >> 4;
    const int l16  = lane & 15;
    {
        int m = m0 + lane; if (m > M - 1) m = M - 1;
        const u16* ab = A  + (size_t)m * 192;
        const u16* wb = Wt + (size_t)(n0 + lane) * 192;
        #pragma unroll
        for (int i = 0; i < 6; ++i) {
            int g = w * 6 + i;              // 0..23, covers k = g*8..g*8+7
            async16(ab + g * 8, als + g * 512);
            async16(wb + g * 8, wls + g * 512);
        }
    }
    __syncthreads();
    f32x4 acc[4];
    #pragma unroll
    for (int mt = 0; mt < 4; ++mt) acc[mt] = (f32x4){0,0,0,0};
    #pragma unroll
    for (int cc = 0; cc < 6; ++cc) {
        bf16x8 bf = *(const bf16x8*)(wls + (((cc * 4 + quad) * 64) + w * 16 + l16) * 8);
        #pragma unroll
        for (int mt = 0; mt < 4; ++mt) {
            bf16x8 af = *(const bf16x8*)(als + (((cc * 4 + quad) * 64) + mt * 16 + l16) * 8);
            acc[mt] = __builtin_amdgcn_mfma_f32_16x16x32_bf16(af, bf, acc[mt], 0, 0, 0);
        }
    }
    float bj = bias[n0 + w * 16 + l16];
    #pragma unroll
    for (int mt = 0; mt < 4; ++mt) {
        #pragma unroll
        for (int rr = 0; rr < 4; ++rr) {
            int row = m0 + mt * 16 + quad * 4 + rr;
            if (row < M) {
                float v = acc[mt][rr] + bj;
                size_t off = (size_t)row * ldo + n0 + w * 16 + l16;
                if (outb) outb[off] = f2b(v);
                else      outf[off] = v;
            }
        }
    }
}

// ------------- Kernel 2: pool+LN v6 (R9-exact, proven 67.0us) ------------------------
__global__ __launch_bounds__(192) void pool_ln6(
    const u16* __restrict__ qkvb, const float* __restrict__ wT,
    const float* __restrict__ gq, const float* __restrict__ bq,
    const float* __restrict__ gk, const float* __restrict__ bk,
    const float* __restrict__ gv, const float* __restrict__ bv,
    const float* __restrict__ rel_h, const float* __restrict__ rel_w,
    const float* __restrict__ rel_t,
    u16* __restrict__ qbb, u16* __restrict__ kx, u16* __restrict__ vbb,
    float* __restrict__ bt, float* __restrict__ bh, float* __restrict__ bw)
{
    // sls[(rr*6+xx)*3 + wseg][96]: rr=(dt+1)*3+(dy+1), xx=0..5, wseg=q/k/v.
    // 1944 16B-chunks padded to 1984 (31744 B).
    __shared__ __align__(16) u16 sls[15872];
    __shared__ __align__(16) float qls[4][96];
    const int h   = blockIdx.x / NSTRIP;
    const int s   = blockIdx.x % NSTRIP;
    const int wid  = threadIdx.x / 64;   // which: 0=q 1=k 2=v
    const int lane = threadIdx.x & 63;
    const bool two = (lane < 32);

    const float* gg = wid == 0 ? gq : (wid == 1 ? gk : gv);
    const float* bb = wid == 0 ? bq : (wid == 1 ? bk : bv);
    const float g0 = gg[lane], b0 = bb[lane];
    const float g1 = two ? gg[64 + lane] : 0.f;
    const float b1 = two ? bb[64 + lane] : 0.f;
    const int col0 = wid * DIM + h * HD;

    if (s == 0) {
        float v0 = b2f(qkvb[col0 + lane]);
        float v1 = two ? b2f(qkvb[col0 + 64 + lane]) : 0.f;
        float s1 = v0 + v1, s2 = v0 * v0 + v1 * v1;
        #pragma unroll
        for (int off = 32; off >= 1; off >>= 1) {
            s1 += __shfl_xor(s1, off);
            s2 += __shfl_xor(s2, off);
        }
        float m = s1 * (1.f / HD);
        float inv = rsqrtf(s2 * (1.f / HD) - m * m + EPS_);
        float o0 = (v0 - m) * inv * g0 + b0;
        float o1 = (v1 - m) * inv * g1 + b1;
        size_t off0 = (size_t)h * NTOKS * HD + lane;
        if (wid == 0) {
            qbb[off0] = f2b(o0 * SCALE2_);
            if (two) qbb[off0 + 64] = f2b(o1 * SCALE2_);
        } else if (wid == 1) {
            size_t kb = (size_t)h * NTOKS * KCH;
            kx[kb + lane] = f2b(o0);
            if (two) kx[kb + 64 + lane] = f2b(o1);
            kx[kb + 96 + lane] = 0;              // cls: no one-hot bias channels
        } else {
            vbb[off0] = f2b(o0);
            if (two) vbb[off0 + 64] = f2b(o1);
        }
        return;
    }

    const int ss = s - 1;
    const int t  = ss / 196;
    const int rm = ss % 196;
    const int y  = rm / 7;
    const int x0 = (rm % 7) * 4;

    // ---- stage the input slab: 31 wave-rounds of 64 async16 chunks over 3 waves ----
    for (int r = wid; r < 31; r += 3) {
        int cbase = r * 64;
        int c = cbase + lane; if (c > 1943) c = 1943;   // clamp src; dest goes to pad
        int rrxx = c / 36, rem = c - rrxx * 36;
        int wseg = rem / 12, ck = rem - wseg * 12;
        int rr = rrxx / 6, xx = rrxx - rr * 6;
        int tt = t + rr / 3 - 1; tt = tt < 0 ? 0 : (tt > T_ - 1 ? T_ - 1 : tt);
        int yy = y + rr % 3 - 1; yy = yy < 0 ? 0 : (yy > H_ - 1 ? H_ - 1 : yy);
        int xp = x0 - 1 + xx;    int xc = xp < 0 ? 0 : (xp > W_ - 1 ? W_ - 1 : xp);
        int tok = 1 + (tt * H_ + yy) * W_ + xc;
        const u16* src = qkvb + (size_t)tok * 576 + wseg * DIM + h * HD + ck * 8;
        async16(src, sls + cbase * 8);
    }
    __syncthreads();

    const float* wslice = wT + wid * 2592;   // [27][96]
    float v0a[4] = {0,0,0,0}, v1a[4] = {0,0,0,0};

    #pragma unroll
    for (int dt = -1; dt <= 1; ++dt) {
        int tt = t + dt; if (tt < 0 || tt >= T_) continue;
        #pragma unroll
        for (int dy = -1; dy <= 1; ++dy) {
            int yy = y + dy; if (yy < 0 || yy >= H_) continue;
            int wb = (dt + 1) * 9 + (dy + 1) * 3;
            int rr = (dt + 1) * 3 + (dy + 1);
            float wa[3], wbh[3];
            #pragma unroll
            for (int o = 0; o < 3; ++o) {
                wa[o]  = wslice[(wb + o) * 96 + lane];
                wbh[o] = two ? wslice[(wb + o) * 96 + 64 + lane] : 0.f;
            }
            #pragma unroll
            for (int i = 0; i < 6; ++i) {
                int xp = x0 - 1 + i;
                if (xp < 0 || xp >= W_) continue;    // wave-uniform guard
                const u16* rbase = sls + (rr * 18 + i * 3 + wid) * 96;
                float r0 = b2f(rbase[lane]);
                float r1 = two ? b2f(rbase[64 + lane]) : 0.f;
                #pragma unroll
                for (int j = 0; j < 4; ++j) {
                    int o = i - j;
                    if (o >= 0 && o <= 2) {
                        v0a[j] += wa[o] * r0;
                        v1a[j] += wbh[o] * r1;
                    }
                }
            }
        }
    }

    #pragma unroll
    for (int j = 0; j < 4; ++j) {
        float s1 = v0a[j] + v1a[j];
        float s2 = v0a[j] * v0a[j] + v1a[j] * v1a[j];
        #pragma unroll
        for (int off = 32; off >= 1; off >>= 1) {
            s1 += __shfl_xor(s1, off);
            s2 += __shfl_xor(s2, off);
        }
        float m = s1 * (1.f / HD);
        float inv = rsqrtf(s2 * (1.f / HD) - m * m + EPS_);
        float o0 = (v0a[j] - m) * inv * g0 + b0;
        float o1 = (v1a[j] - m) * inv * g1 + b1;
        int xj  = x0 + j;
        int tok = 1 + (t * H_ + y) * W_ + xj;
        size_t off0 = ((size_t)h * NTOKS + tok) * HD + lane;
        if (wid == 0) {
            qbb[off0] = f2b(o0 * SCALE2_);
            qls[j][lane] = o0;
            if (two) { qbb[off0 + 64] = f2b(o1 * SCALE2_); qls[j][64 + lane] = o1; }
        } else if (wid == 1) {
            size_t kb = ((size_t)h * NTOKS + tok) * KCH;
            kx[kb + lane] = f2b(o0);
            if (two) kx[kb + 64 + lane] = f2b(o1);
            // one-hot bias channels (96..159): kt=t, kh=y, kw=xj
            int match = (lane < 8) ? (lane == t) : (lane < 36) ? (lane - 8 == y) : (lane - 36 == xj);
            kx[kb + 96 + lane] = match ? (u16)0x3F80 : (u16)0;
        } else {
            vbb[off0] = f2b(o0);
            if (two) vbb[off0 + 64] = f2b(o1);
        }
    }

    if (threadIdx.x < 64) {
        int tq = threadIdx.x;
        #pragma unroll
        for (int j = 0; j < 4; ++j) {
            int sp = (t * H_ + y) * W_ + x0 + j;   // tok-1
            const float* row;
            float* outp;
            if (tq < 8)       { row = rel_t + (size_t)(t - tq        + (T_ - 1)) * HD; outp = bt + ((size_t)h*NSP + sp)*8  + tq;      }
            else if (tq < 36) { row = rel_h + (size_t)(y - (tq - 8)  + (H_ - 1)) * HD; outp = bh + ((size_t)h*NSP + sp)*28 + (tq-8);  }
            else              { row = rel_w + (size_t)(x0 + j - (tq - 36) + (W_ - 1)) * HD; outp = bw + ((size_t)h*NSP + sp)*28 + (tq-36); }
            const float4* r4 = (const float4*)row;
            const float4* q4 = (const float4*)qls[j];
            float acc = 0.f;
            #pragma unroll
            for (int i = 0; i < 24; ++i) {
                float4 a = q4[i], b = r4[i];
                acc += a.x*b.x + a.y*b.y + a.z*b.z + a.w*b.w;
            }
            *outp = acc;
        }
    }
}

// ------------- Kernel 2b: transpose V to [h][c][tok] (coalesced, proven cheap) -------
__global__ __launch_bounds__(256) void vtrans(
    const u16* __restrict__ vbb, u16* __restrict__ vbT)
{
    __shared__ u16 tls[128][104];
    int h  = blockIdx.y;
    int t0 = blockIdx.x * 128;
    int tid = threadIdx.x;
    #pragma unroll
    for (int it = 0; it < 24; ++it) {           // 128*48 dwords
        int idx = tid + it * 256;
        int row = idx / 48, col = idx % 48;
        int tok = t0 + row; if (tok > NTOKS - 1) tok = NTOKS - 1;
        *(u32*)&tls[row][col*2] = *(const u32*)(vbb + ((size_t)h * NTOKS + tok) * HD + col*2);
    }
    __syncthreads();
    #pragma unroll
    for (int it = 0; it < 24; ++it) {           // 96*64 dwords
        int idx = tid + it * 256;
        int c = idx / 64, tp = idx % 64;
        u32 lo = tls[tp*2][c], hi = tls[tp*2+1][c];
        *(u32*)(vbT + ((size_t)h * HD + c) * VT_LD + t0 + tp*2) = lo | (hi << 16);
    }
}

// ------------- Kernel 4: MFMA flash attention v10 (QT=256, 1024 threads) -------------
// R13 traffic model: K/V re-read = 500 blocks x 640KB = 320MB @ ~4.7 TB/s from L2/L3
// — the plausible binding resource (QT 64->128 already showed per-tile wall grows only
// 1.4x when traffic/work halves). v10: QT=256 halves K/V traffic again (160MB).
// 250 blocks, 1/CU (LDS 96KB), 16 waves/CU (same occupancy as v9's 2x8). pls grows
// to [256] rows, same XOR swizzle; staging = 2 chunks/wave; else byte-identical.
__global__ __launch_bounds__(1024) void attn_mfma4(
    const u16* __restrict__ qbb, const u16* __restrict__ kx,
    const u16* __restrict__ vbT,
    const float* __restrict__ btp, const float* __restrict__ bhp,
    const float* __restrict__ bwp,
    u16* __restrict__ pO, float* __restrict__ pl)
{
    __shared__ __align__(16) u16 kls[2][20 * 512];  // 40 KB
    __shared__ __align__(16) u16 vls[2][12 * 512];  // 24 KB
    __shared__ __align__(16) u16 pls[256 * 64];     // 32 KB (XOR-swizzled)

    const int g     = blockIdx.x % (HEADS * NSPL);
    const int qb    = blockIdx.x / (HEADS * NSPL);
    const int h     = g / NSPL;
    const int split = g % NSPL;
    const int q0    = qb * QT;
    const int tid   = threadIdx.x;
    const int w     = tid >> 6;          // 0..15
    const int lane  = tid & 63;
    const int quad  = lane >> 4;
    const int l16   = lane & 15;

    const int t0 = split * SPT;
    const int t1 = (t0 + SPT < NTILES_TOT) ? t0 + SPT : NTILES_TOT;

    // 32 staging chunks (20 K + 12 V) over 16 waves, 2 each; wave-uniform branch.
    auto stage = [&](int buf, int tile) {
        int kb0 = tile * KT;
        int key = kb0 + lane; if (key > NTOKS - 1) key = NTOKS - 1;
        const u16* gbase = kx + ((size_t)h * NTOKS + key) * KCH;
        #pragma unroll
        for (int i = 0; i < 2; ++i) {
            int c = w * 2 + i;
            if (c < 20) {
                int c5 = c >> 2, qd = c & 3;
                async16(gbase + c5 * 32 + qd * 8, kls[buf] + c * 512);
            } else {
                int CH2 = c - 20;
                int E = CH2 * 64 + lane;
                int kcq = E / 96, n = E - kcq * 96;
                int kc = kcq >> 2, qd = kcq & 3;
                const u16* src = vbT + ((size_t)h * HD + n) * VT_LD + kb0 + kc * 32 + qd * 8;
                async16(src, vls[buf] + CH2 * 512);
            }
        }
    };

    stage(0, t0);

    bf16x8 aq[5];
    {
        int tokc = q0 + w * 16 + l16;
        int tq = tokc > NTOKS - 1 ? NTOKS - 1 : tokc;
        const u16* qrow = qbb + ((size_t)h * NTOKS + tq) * HD;
        #pragma unroll
        for (int cc = 0; cc < 3; ++cc)
            aq[cc] = *(const bf16x8*)(qrow + cc * 32 + quad * 8);
        bool has = (tokc >= 1 && tokc < NTOKS);
        int sp = tokc - 1;
        #pragma unroll
        for (int cc = 3; cc < 5; ++cc) {
            bf16x8 tf;
            #pragma unroll
            for (int j = 0; j < 8; ++j) {
                int kk = (cc - 3) * 32 + quad * 8 + j;
                float v = 0.f;
                if (has) {
                    if (kk < 8)       v = btp[((size_t)h * NSP + sp) * 8  + kk];
                    else if (kk < 36) v = bhp[((size_t)h * NSP + sp) * 28 + (kk - 8)];
                    else              v = bwp[((size_t)h * NSP + sp) * 28 + (kk - 36)];
                }
                tf[j] = (short)f2b(v * LOG2E_);   // exp2-domain bias
            }
            aq[cc] = tf;
        }
    }

    f32x4 accO[6];
    #pragma unroll
    for (int nt = 0; nt < 6; ++nt) accO[nt] = (f32x4){0,0,0,0};
    float psum[4] = {0.f, 0.f, 0.f, 0.f};

    for (int tile = t0; tile < t1; ++tile) {
        const int cur = (tile - t0) & 1;
        __syncthreads();
        if (tile + 1 < t1) stage(cur ^ 1, tile + 1);
        const int kb0 = tile * KT;
        const u16* kcur = kls[cur];
        const u16* vcur = vls[cur];
        f32x4 sacc[4];
        #pragma unroll
        for (int nt = 0; nt < 4; ++nt) sacc[nt] = (f32x4){0,0,0,0};
        __builtin_amdgcn_s_setprio(1);
        #pragma unroll
        for (int cc = 0; cc < 5; ++cc) {
            #pragma unroll
            for (int nt = 0; nt < 4; ++nt) {
                bf16x8 bk = *(const bf16x8*)(kcur + (((cc * 4 + quad) * 64) + nt * 16 + l16) * 8);
                sacc[nt] = __builtin_amdgcn_mfma_f32_16x16x32_bf16(aq[cc], bk, sacc[nt], 0, 0, 0);
            }
        }
        __builtin_amdgcn_s_setprio(0);
        const int r0 = w * 16 + quad * 4;
        #pragma unroll
        for (int nt = 0; nt < 4; ++nt) {
            int keyg = kb0 + nt * 16 + l16;
            bool ok = keyg < NTOKS;
            float e0, e1, e2, e3;
            asm("v_exp_f32 %0, %1" : "=v"(e0) : "v"(sacc[nt][0]));
            asm("v_exp_f32 %0, %1" : "=v"(e1) : "v"(sacc[nt][1]));
            asm("v_exp_f32 %0, %1" : "=v"(e2) : "v"(sacc[nt][2]));
            asm("v_exp_f32 %0, %1" : "=v"(e3) : "v"(sacc[nt][3]));
            e0 = ok ? e0 : 0.f; e1 = ok ? e1 : 0.f;
            e2 = ok ? e2 : 0.f; e3 = ok ? e3 : 0.f;
            psum[0] += e0; psum[1] += e1; psum[2] += e2; psum[3] += e3;
            u32 p01, p23;
            asm("v_cvt_pk_bf16_f32 %0, %1, %2" : "=v"(p01) : "v"(e0), "v"(e1));
            asm("v_cvt_pk_bf16_f32 %0, %1, %2" : "=v"(p23) : "v"(e2), "v"(e3));
            const int colb = nt * 32 + l16 * 2;
            *(u16*)((char*)pls + (r0+0) * 128 + (colb ^ (((r0+0) & 7) << 4))) = (u16)p01;
            *(u16*)((char*)pls + (r0+1) * 128 + (colb ^ (((r0+1) & 7) << 4))) = (u16)(p01 >> 16);
            *(u16*)((char*)pls + (r0+2) * 128 + (colb ^ (((r0+2) & 7) << 4))) = (u16)p23;
            *(u16*)((char*)pls + (r0+3) * 128 + (colb ^ (((r0+3) & 7) << 4))) = (u16)(p23 >> 16);
        }
        __builtin_amdgcn_s_setprio(1);
        #pragma unroll
        for (int kc = 0; kc < 2; ++kc) {
            int prow = w * 16 + l16;
            int pbyte = prow * 128 + ((kc * 64 + quad * 16) ^ ((prow & 7) << 4));
            bf16x8 ap = *(const bf16x8*)((const char*)pls + pbyte);
            #pragma unroll
            for (int nt = 0; nt < 6; ++nt) {
                bf16x8 bv = *(const bf16x8*)(vcur + (((kc * 4 + quad) * 96) + nt * 16 + l16) * 8);
                accO[nt] = __builtin_amdgcn_mfma_f32_16x16x32_bf16(ap, bv, accO[nt], 0, 0, 0);
            }
        }
        __builtin_amdgcn_s_setprio(0);
    }

    #pragma unroll
    for (int off = 1; off < 16; off <<= 1) {
        #pragma unroll
        for (int rr = 0; rr < 4; ++rr)
            psum[rr] += __shfl_xor(psum[rr], off);
    }
    const int sh = split * HEADS + h;
    if (l16 == 0) {
        #pragma unroll
        for (int rr = 0; rr < 4; ++rr) {
            int tok = q0 + w * 16 + quad * 4 + rr;
            if (tok < NTOKS)
                pl[(size_t)sh * NTOKS + tok] = psum[rr];
        }
    }
    #pragma unroll
    for (int rr = 0; rr < 4; ++rr) {
        int tok = q0 + w * 16 + quad * 4 + rr;
        if (tok >= NTOKS) continue;
        #pragma unroll
        for (int nt = 0; nt < 6; ++nt)
            pO[((size_t)sh * NTOKS + tok) * HD + nt * 16 + l16] = f2b(accO[nt][rr]);
    }
}

// ------- Kernel 4b: combine bf16 k-split partials + bf16 residual -> bf16 pre -------
__global__ __launch_bounds__(256) void combine(
    const u16* __restrict__ pO, const float* __restrict__ pl,
    const u16* __restrict__ qbb, u16* __restrict__ preb)
{
    int i = blockIdx.x * 256 + threadIdx.x;   // pair index: (tok, channel-pair)
    const int NP = NTOKS * 96;
    if (i >= NP) return;
    int tok = i / 96, dp = i - tok * 96;
    int d0 = dp * 2;
    int hh = d0 / HD, c0 = d0 - hh * HD;
    float l = 0.f, o0 = 0.f, o1 = 0.f;
    #pragma unroll
    for (int s = 0; s < NSPL; ++s) {
        l += pl[(size_t)(s * HEADS + hh) * NTOKS + tok];
        u32 pr = *(const u32*)(pO + ((size_t)(s * HEADS + hh) * NTOKS + tok) * HD + c0);
        o0 += b2f((u16)(pr & 0xffffu));
        o1 += b2f((u16)(pr >> 16));
    }
    float v0 = o0 / l, v1 = o1 / l;
    if (tok >= 1) {
        u32 qr = *(const u32*)(qbb + ((size_t)hh * NTOKS + tok) * HD + c0);
        v0 += b2f((u16)(qr & 0xffffu)) * RINV_;
        v1 += b2f((u16)(qr >> 16)) * RINV_;
    }
    u32 pack = (u32)f2b(v0) | ((u32)f2b(v1) << 16);
    *(u32*)(preb + (size_t)tok * DIM + d0) = pack;
}

extern "C" void kernel_launch(void* const* d_in, const int* in_sizes, int n_in,
                              void* d_out, int out_size, void* d_ws, size_t ws_size,
                              hipStream_t stream) {
    (void)in_sizes; (void)n_in; (void)out_size; (void)ws_size;
    const float* x      = (const float*)d_in[0];
    const float* qkv_w  = (const float*)d_in[1];
    const float* qkv_b  = (const float*)d_in[2];
    const float* proj_w = (const float*)d_in[3];
    const float* proj_b = (const float*)d_in[4];
    const float* pool_q = (const float*)d_in[5];
    const float* pool_k = (const float*)d_in[6];
    const float* pool_v = (const float*)d_in[7];
    const float* gq     = (const float*)d_in[8];
    const float* bq     = (const float*)d_in[9];
    const float* gk     = (const float*)d_in[10];
    const float* bk     = (const float*)d_in[11];
    const float* gv     = (const float*)d_in[12];
    const float* bv     = (const float*)d_in[13];
    const float* rel_h  = (const float*)d_in[14];
    const float* rel_w  = (const float*)d_in[15];
    const float* rel_t  = (const float*)d_in[16];

    char* p = (char*)d_ws;
    auto alloc = [&](size_t bytes) -> void* {
        void* r = (void*)p; p += (bytes + 255) & ~(size_t)255; return r;
    };
    u16*   qkvb = (u16*) alloc((size_t)NTOKS * 576 * 2);
    u16*   qbb = (u16*)  alloc((size_t)HEADS * NTOKS * HD * 2);
    u16*   kxb = (u16*)  alloc((size_t)HEADS * NTOKS * KCH * 2);
    u16*   vbb = (u16*)  alloc((size_t)HEADS * NTOKS * HD * 2);
    u16*   vbT = (u16*)  alloc((size_t)HEADS * HD * VT_LD * 2);
    float* bt  = (float*)alloc((size_t)HEADS * NSP * 8 * 4);
    float* bh  = (float*)alloc((size_t)HEADS * NSP * 28 * 4);
    float* bw  = (float*)alloc((size_t)HEADS * NSP * 28 * 4);
    u16*   pO  = (u16*)  alloc((size_t)NSPL * HEADS * NTOKS * HD * 2);
    float* pl  = (float*)alloc((size_t)NSPL * HEADS * NTOKS * 4);
    u16*   xb  = (u16*)  alloc((size_t)NTOKS * DIM * 2);
    u16*   qwb = (u16*)  alloc((size_t)576 * DIM * 2);
    u16*   pwb = (u16*)  alloc((size_t)DIM * DIM * 2);
    u16*   preb= (u16*)  alloc((size_t)NTOKS * DIM * 2);
    float* wT  = (float*)alloc((size_t)3 * 27 * 96 * 4);

    const int nx = NTOKS * DIM, nqw = 576 * DIM, npw = DIM * DIM;
    cvt_bf16<<<1024, 256, 0, stream>>>(x, xb, nx, qkv_w, qwb, nqw, proj_w, pwb, npw,
                                       pool_q, pool_k, pool_v, wT);
    gemm_bf16<<<dim3(99, 9), 256, 0, stream>>>(xb, qwb, qkv_b, nullptr, qkvb, NTOKS, 576);
    pool_ln6<<<HEADS * NSTRIP, 192, 0, stream>>>(
        qkvb, wT, gq, bq, gk, bk, gv, bv,
        rel_h, rel_w, rel_t, qbb, kxb, vbb, bt, bh, bw);
    vtrans<<<dim3((NTOKS + 127) / 128, HEADS), 256, 0, stream>>>(vbb, vbT);
    attn_mfma4<<<QB * HEADS * NSPL, 1024, 0, stream>>>(qbb, kxb, vbT, bt, bh, bw, pO, pl);
    combine<<<(NTOKS * 96 + 255) / 256, 256, 0, stream>>>(pO, pl, qbb, preb);
    gemm_bf16<<<dim3(99, 3), 256, 0, stream>>>(preb, pwb, proj_b, (float*)d_out, nullptr, NTOKS, 192);
}